// Round 3
// baseline (298.870 us; speedup 1.0000x reference)
//
#include <hip/hip_runtime.h>
#include <hip/hip_cooperative_groups.h>
#include <math.h>

namespace cg = cooperative_groups;

// Problem constants (fixed by setup_inputs)
constexpr int HOPS  = 3;
constexpr int VOCAB = 50257;
constexpr int DIM   = 128;
constexpr int NB    = 32;         // batch
constexpr int NM    = 512;        // story slots
constexpr int NS    = 6;          // tokens per story slot
constexpr int NT    = 128;        // trees
constexpr int NL    = 64;         // tokens per tree
constexpr int SLOTS = NM + NT;    // 640
constexpr size_t TS = (size_t)VOCAB * DIM;              // fp32 table stride in C
constexpr size_t TABSTRIDE = (size_t)NB * SLOTS * DIM;  // msum per-table stride (fp16 elems)

// fp16 compressed tables, token-interleaved: Ch[v][tab][d], tab 0..2 = C[1..3].
constexpr size_t CH_ELEMS = (size_t)VOCAB * 3 * DIM;    // 19,298,688
constexpr int NE8 = (int)(CH_ELEMS / 8);                // 2,412,336 half8 groups

typedef _Float16 half8 __attribute__((ext_vector_type(8)));

constexpr int GRID = 256;         // one 1024-thread block per CU; co-resident

// ---------------------------------------------------------------------------
// Single cooperative kernel, three phases separated by grid.sync():
//  phase 1: convert C[1..3] fp32 -> Ch fp16 interleaved [V][3][128] (grid-stride)
//  phase 2: gathers from fp16 Ch. Per block: 16 trees (one per wave) + 64
//           story slots (4 per wave, one per 16-lane quarter).
//  phase 3: blocks 0..31 run the fused hop chain (vc register-cached, 3 table
//           passes), one block per batch element.
// grid.sync() provides the device-scope fence for cross-XCD Ch/msum visibility.
// ---------------------------------------------------------------------------
__global__ __launch_bounds__(1024) void fused_all(
    const float* __restrict__ C, const int* __restrict__ story,
    const int* __restrict__ kb, _Float16* __restrict__ Ch,
    _Float16* __restrict__ msum, float* __restrict__ out)
{
    cg::grid_group grid = cg::this_grid();
    const int t = threadIdx.x;
    const int wave = t >> 6, lane = t & 63;
    const int q = lane >> 4, l16 = lane & 15;

    // ---------------- phase 1: convert ----------------
    for (int e8 = blockIdx.x * 1024 + t; e8 < NE8; e8 += GRID * 1024) {
        const size_t base = (size_t)e8 * 8;
        const size_t v    = base / 384;
        const int    rem  = (int)(base % 384);
        const int    tab  = rem >> 7;             // 0..2
        const int    d    = rem & 127;            // 8-aligned
        const float* src = C + (size_t)(1 + tab) * TS + v * DIM + d;
        float4 f0 = *(const float4*)(src);
        float4 f1 = *(const float4*)(src + 4);
        half8 h;
        h[0]=(_Float16)f0.x; h[1]=(_Float16)f0.y; h[2]=(_Float16)f0.z; h[3]=(_Float16)f0.w;
        h[4]=(_Float16)f1.x; h[5]=(_Float16)f1.y; h[6]=(_Float16)f1.z; h[7]=(_Float16)f1.w;
        *(half8*)(Ch + base) = h;
    }

    grid.sync();

    // ---------------- phase 2: gather ----------------
    {
        // ---- tree: one per wave. 4 quarters x 16 tokens; lane l16 owns dims
        //      [l16*8, l16*8+8); cross-quarter shfl-xor reduce; quarter 0 writes.
        const int g = blockIdx.x * 16 + wave;         // b*NT + tree, 0..4095
        const int b = g >> 7, tr = g & (NT - 1);

        const int tok = kb[(size_t)g * NL + lane];    // coalesced 64-token load

        float a0[8] = {0,0,0,0,0,0,0,0};
        float a1[8] = {0,0,0,0,0,0,0,0};
        float a2[8] = {0,0,0,0,0,0,0,0};

        #pragma unroll
        for (int i = 0; i < 16; ++i) {
            const int s = __shfl(tok, (lane & 48) + i);   // token q*16+i of my tree
            const _Float16* p = Ch + (size_t)s * (3 * DIM) + l16 * 8;
            half8 v0 = *(const half8*)(p);
            half8 v1 = *(const half8*)(p + DIM);
            half8 v2 = *(const half8*)(p + 2 * DIM);
            #pragma unroll
            for (int j = 0; j < 8; ++j) {
                a0[j] = fmaf((float)v0[j], 1.0f, a0[j]);
                a1[j] = fmaf((float)v1[j], 1.0f, a1[j]);
                a2[j] = fmaf((float)v2[j], 1.0f, a2[j]);
            }
        }
        #pragma unroll
        for (int j = 0; j < 8; ++j) {
            a0[j] += __shfl_xor(a0[j], 16); a0[j] += __shfl_xor(a0[j], 32);
            a1[j] += __shfl_xor(a1[j], 16); a1[j] += __shfl_xor(a1[j], 32);
            a2[j] += __shfl_xor(a2[j], 16); a2[j] += __shfl_xor(a2[j], 32);
        }
        if (q == 0) {
            half8 h0, h1, h2;
            #pragma unroll
            for (int j = 0; j < 8; ++j) {
                h0[j] = (_Float16)a0[j]; h1[j] = (_Float16)a1[j]; h2[j] = (_Float16)a2[j];
            }
            const size_t o = ((size_t)b * SLOTS + NM + tr) * DIM + l16 * 8;
            *(half8*)(msum + o)                 = h0;
            *(half8*)(msum + o + TABSTRIDE)     = h1;
            *(half8*)(msum + o + 2 * TABSTRIDE) = h2;
        }

        // ---- story: 4 slots per wave, one per 16-lane quarter ----
        const int wbase = blockIdx.x * 64 + wave * 4;     // first slot of wave
        const int* sidx = story + (size_t)wbase * NS;
        const int tokv = (lane < 4 * NS) ? sidx[lane] : 0;   // 24 coalesced ints

        const int gs = wbase + q;                  // b*NM + slot, 0..16383
        const int bs = gs >> 9, slot = gs & (NM - 1);

        float b0[8] = {0,0,0,0,0,0,0,0};
        float b1[8] = {0,0,0,0,0,0,0,0};
        float b2[8] = {0,0,0,0,0,0,0,0};

        #pragma unroll
        for (int i = 0; i < NS; ++i) {
            const int s = __shfl(tokv, q * NS + i);
            const _Float16* p = Ch + (size_t)s * (3 * DIM) + l16 * 8;
            half8 v0 = *(const half8*)(p);
            half8 v1 = *(const half8*)(p + DIM);
            half8 v2 = *(const half8*)(p + 2 * DIM);
            #pragma unroll
            for (int j = 0; j < 8; ++j) {
                b0[j] = fmaf((float)v0[j], 1.0f, b0[j]);
                b1[j] = fmaf((float)v1[j], 1.0f, b1[j]);
                b2[j] = fmaf((float)v2[j], 1.0f, b2[j]);
            }
        }
        half8 h0, h1, h2;
        #pragma unroll
        for (int j = 0; j < 8; ++j) {
            h0[j] = (_Float16)b0[j]; h1[j] = (_Float16)b1[j]; h2[j] = (_Float16)b2[j];
        }
        const size_t o = ((size_t)bs * SLOTS + slot) * DIM + l16 * 8;
        *(half8*)(msum + o)                 = h0;
        *(half8*)(msum + o + TABSTRIDE)     = h1;
        *(half8*)(msum + o + 2 * TABSTRIDE) = h2;
    }

    grid.sync();

    // ---------------- phase 3: hops (blocks 0..31) ----------------
    if (blockIdx.x < NB) {
        const int b = blockIdx.x;
        const int rg = t >> 4, wv = t >> 6, ln = t & 63;
        __shared__ float u_s[DIM];
        __shared__ float probs[SLOTS];
        __shared__ float part[64][DIM + 4];   // 33.8 KB; +4 pad -> 4*rg bank skew
        __shared__ float red[16];

        const _Float16* base = msum + (size_t)b * SLOTS * DIM;
        const int doff = l16 * 8;

        half8 vc[10];                         // 40 VGPR row cache, static indexing

        // ---- pass A: load tab0 rows, hop0 mean -> u ----
        {
            float acc[8] = {0,0,0,0,0,0,0,0};
            #pragma unroll
            for (int r = 0; r < 10; ++r)
                vc[r] = *(const half8*)(base + (size_t)(rg + 64 * r) * DIM + doff);
            #pragma unroll
            for (int r = 0; r < 10; ++r) {
                #pragma unroll
                for (int j = 0; j < 8; ++j) acc[j] += (float)vc[r][j];
            }
            #pragma unroll
            for (int j = 0; j < 8; ++j) part[rg][doff + j] = acc[j];
            __syncthreads();
            if (t < DIM) {
                float s = 0.f;
                #pragma unroll
                for (int r = 0; r < 64; ++r) s += part[r][t];
                u_s[t] = s * (1.f / SLOTS);
            }
            __syncthreads();
        }

        // ---- hops 1..2 ----
        #pragma unroll
        for (int hop = 1; hop < HOPS; ++hop) {
            float u_reg[8];
            #pragma unroll
            for (int j = 0; j < 8; ++j) u_reg[j] = u_s[doff + j];

            // scores from cached rows (tab[hop-1]) -- zero memory traffic
            #pragma unroll
            for (int r = 0; r < 10; ++r) {
                const int m = rg + 64 * r;
                float d = 0.f;
                #pragma unroll
                for (int j = 0; j < 8; ++j) d = fmaf((float)vc[r][j], u_reg[j], d);
                d += __shfl_xor(d, 1); d += __shfl_xor(d, 2);
                d += __shfl_xor(d, 4); d += __shfl_xor(d, 8);
                if (l16 == 0) probs[m] = d;
            }
            __syncthreads();                 // raw scores visible

            // block softmax over SLOTS entries (t<SLOTS owns one)
            float s0 = (t < SLOTS) ? probs[t] : -INFINITY;
            float lmax = s0;
            #pragma unroll
            for (int off = 32; off > 0; off >>= 1) lmax = fmaxf(lmax, __shfl_xor(lmax, off));
            if (ln == 0) red[wv] = lmax;
            __syncthreads();
            lmax = red[0];
            #pragma unroll
            for (int r = 1; r < 16; ++r) lmax = fmaxf(lmax, red[r]);
            __syncthreads();
            float e0 = (t < SLOTS) ? expf(s0 - lmax) : 0.f;
            if (t < SLOTS) probs[t] = e0;
            float lsum = e0;
            #pragma unroll
            for (int off = 32; off > 0; off >>= 1) lsum += __shfl_xor(lsum, off);
            if (ln == 0) red[wv] = lsum;
            __syncthreads();
            float tot = red[0];
            #pragma unroll
            for (int r = 1; r < 16; ++r) tot += red[r];
            const float inv = 1.0f / tot;

            // weighted sum over tab[hop]; reload vc[] (= next hop's score rows)
            const _Float16* mC = base + (size_t)hop * TABSTRIDE;
            float acc[8] = {0,0,0,0,0,0,0,0};
            #pragma unroll
            for (int r = 0; r < 10; ++r) {
                const int m = rg + 64 * r;
                vc[r] = *(const half8*)(mC + (size_t)m * DIM + doff);
                const float p = probs[m];
                #pragma unroll
                for (int j = 0; j < 8; ++j) acc[j] = fmaf(p, (float)vc[r][j], acc[j]);
            }
            __syncthreads();
            #pragma unroll
            for (int j = 0; j < 8; ++j) part[rg][doff + j] = acc[j];
            __syncthreads();
            if (t < DIM) {
                float s = 0.f;
                #pragma unroll
                for (int r = 0; r < 64; ++r) s += part[r][t];
                u_s[t] += s * inv;
            }
            __syncthreads();
        }

        if (t < DIM) out[b * DIM + t] = u_s[t];
    }
}

extern "C" void kernel_launch(void* const* d_in, const int* in_sizes, int n_in,
                              void* d_out, int out_size, void* d_ws, size_t ws_size,
                              hipStream_t stream) {
    const float* C     = (const float*)d_in[0];   // [4][VOCAB][DIM] fp32
    const int*   story = (const int*)d_in[1];     // [32][512][6]
    const int*   kb    = (const int*)d_in[2];     // [32][128][64]
    float*       out   = (float*)d_out;           // [32][128] fp32

    _Float16* Ch   = (_Float16*)d_ws;             // [V][3][128] fp16 = 36.8 MiB
    _Float16* msum = Ch + CH_ELEMS;               // [3][NB][SLOTS][128] fp16 = 15 MiB

    void* args[] = { (void*)&C, (void*)&story, (void*)&kb,
                     (void*)&Ch, (void*)&msum, (void*)&out };
    hipLaunchCooperativeKernel((void*)fused_all, dim3(GRID), dim3(1024),
                               args, 0, stream);
}

// Round 4
// 221.902 us; speedup vs baseline: 1.3469x; 1.3469x over previous
//
#include <hip/hip_runtime.h>
#include <math.h>

// Problem constants (fixed by setup_inputs)
constexpr int HOPS  = 3;
constexpr int VOCAB = 50257;
constexpr int DIM   = 128;
constexpr int NB    = 32;         // batch
constexpr int NM    = 512;        // story slots
constexpr int NS    = 6;          // tokens per story slot
constexpr int NT    = 128;        // trees
constexpr int NL    = 64;         // tokens per tree
constexpr int SLOTS = NM + NT;    // 640
constexpr size_t TS = (size_t)VOCAB * DIM;              // fp32 table stride in C
constexpr size_t TABSTRIDE = (size_t)NB * SLOTS * DIM;  // msum per-table stride (fp16 elems)

// fp16 compressed tables, token-interleaved: Ch[v][tab][d], tab 0..2 = C[1..3].
constexpr size_t CH_ELEMS = (size_t)VOCAB * 3 * DIM;    // 19,298,688
constexpr int NE8 = (int)(CH_ELEMS / 8);                // 2,412,336 half8 groups

typedef _Float16 half8 __attribute__((ext_vector_type(8)));

constexpr int CONV_BLOCKS   = 2048;   // pure streaming converter
constexpr int GATHER_BLOCKS = 2048;   // 2 trees + 8 story slots per block

// ---------------------------------------------------------------------------
// Kernel 1: pure fp32 -> fp16 conversion, C[1..3] -> Ch interleaved [V][3][128].
// Fully coalesced stream: 77 MB read + 39 MB write, HBM-bound (~19 us).
// ---------------------------------------------------------------------------
__global__ __launch_bounds__(256) void convert_k(
    const float* __restrict__ C, _Float16* __restrict__ Ch)
{
    for (int e8 = blockIdx.x * 256 + threadIdx.x; e8 < NE8; e8 += CONV_BLOCKS * 256) {
        const size_t base = (size_t)e8 * 8;
        const size_t v    = base / 384;
        const int    rem  = (int)(base % 384);
        const int    tab  = rem >> 7;             // 0..2
        const int    d    = rem & 127;            // 8-aligned
        const float* src = C + (size_t)(1 + tab) * TS + v * DIM + d;
        float4 f0 = *(const float4*)(src);
        float4 f1 = *(const float4*)(src + 4);
        half8 h;
        h[0]=(_Float16)f0.x; h[1]=(_Float16)f0.y; h[2]=(_Float16)f0.z; h[3]=(_Float16)f0.w;
        h[4]=(_Float16)f1.x; h[5]=(_Float16)f1.y; h[6]=(_Float16)f1.z; h[7]=(_Float16)f1.w;
        *(half8*)(Ch + base) = h;
    }
}

// ---------------------------------------------------------------------------
// Kernel 2: gathers from fp16 Ch, restructured for deep memory-level
// parallelism. Tokens come straight from kb/story (no dependent loads), so
// the only MLP cap is destination registers: launch_bounds(256,4) allows 128
// VGPR; loads are issued in chunks (12 for tree, 9 for story) before any
// consumption. Accumulation order identical to the serial version.
//  waves 0..1: one tree per wave (4 quarters x 16 tokens, 4-row chunks).
//  waves 2..3: 4 story slots per wave, one per 16-lane quarter (3-row chunks).
// ---------------------------------------------------------------------------
__global__ __launch_bounds__(256, 4) void gather_k(
    const _Float16* __restrict__ Ch, const int* __restrict__ story,
    const int* __restrict__ kb, _Float16* __restrict__ msum)
{
    const int wave = threadIdx.x >> 6, lane = threadIdx.x & 63;
    const int q = lane >> 4, l16 = lane & 15;

    if (wave < 2) {
        // ---- tree gather: g = b*NT + tree in [0, 4096) ----
        const int g = blockIdx.x * 2 + wave;
        const int b = g >> 7, tr = g & (NT - 1);

        const int tok = kb[(size_t)g * NL + lane];    // coalesced 64-token load

        float a0[8] = {0,0,0,0,0,0,0,0};
        float a1[8] = {0,0,0,0,0,0,0,0};
        float a2[8] = {0,0,0,0,0,0,0,0};

        #pragma unroll
        for (int c = 0; c < 4; ++c) {
            const _Float16* p[4];
            #pragma unroll
            for (int k = 0; k < 4; ++k) {
                const int s = __shfl(tok, (lane & 48) + c * 4 + k);
                p[k] = Ch + (size_t)s * (3 * DIM) + l16 * 8;
            }
            half8 v[12];                 // 48 VGPR of in-flight loads
            #pragma unroll
            for (int k = 0; k < 4; ++k) {
                v[3*k+0] = *(const half8*)(p[k]);
                v[3*k+1] = *(const half8*)(p[k] + DIM);
                v[3*k+2] = *(const half8*)(p[k] + 2 * DIM);
            }
            #pragma unroll
            for (int k = 0; k < 4; ++k) {
                #pragma unroll
                for (int j = 0; j < 8; ++j) {
                    a0[j] = fmaf((float)v[3*k+0][j], 1.0f, a0[j]);
                    a1[j] = fmaf((float)v[3*k+1][j], 1.0f, a1[j]);
                    a2[j] = fmaf((float)v[3*k+2][j], 1.0f, a2[j]);
                }
            }
        }
        // reduce the 4 quarter-partials (lanes differ only in q bits 4..5)
        #pragma unroll
        for (int j = 0; j < 8; ++j) {
            a0[j] += __shfl_xor(a0[j], 16); a0[j] += __shfl_xor(a0[j], 32);
            a1[j] += __shfl_xor(a1[j], 16); a1[j] += __shfl_xor(a1[j], 32);
            a2[j] += __shfl_xor(a2[j], 16); a2[j] += __shfl_xor(a2[j], 32);
        }
        if (q == 0) {
            half8 h0, h1, h2;
            #pragma unroll
            for (int j = 0; j < 8; ++j) {
                h0[j] = (_Float16)a0[j]; h1[j] = (_Float16)a1[j]; h2[j] = (_Float16)a2[j];
            }
            const size_t o = ((size_t)b * SLOTS + NM + tr) * DIM + l16 * 8;
            *(half8*)(msum + o)                 = h0;
            *(half8*)(msum + o + TABSTRIDE)     = h1;
            *(half8*)(msum + o + 2 * TABSTRIDE) = h2;
        }
    } else {
        // ---- story gather: 8 slots per block, 4 per wave, 1 per quarter ----
        const int wbase = blockIdx.x * 8 + (wave - 2) * 4;   // first slot of wave
        const int* sidx = story + (size_t)wbase * NS;
        const int tokv = (lane < 4 * NS) ? sidx[lane] : 0;   // 24 coalesced ints

        const int g = wbase + q;                  // b*NM + slot
        const int b = g >> 9, slot = g & (NM - 1);

        float a0[8] = {0,0,0,0,0,0,0,0};
        float a1[8] = {0,0,0,0,0,0,0,0};
        float a2[8] = {0,0,0,0,0,0,0,0};

        #pragma unroll
        for (int c = 0; c < 2; ++c) {
            const _Float16* p[3];
            #pragma unroll
            for (int k = 0; k < 3; ++k) {
                const int s = __shfl(tokv, q * NS + c * 3 + k);
                p[k] = Ch + (size_t)s * (3 * DIM) + l16 * 8;
            }
            half8 v[9];                  // 36 VGPR of in-flight loads
            #pragma unroll
            for (int k = 0; k < 3; ++k) {
                v[3*k+0] = *(const half8*)(p[k]);
                v[3*k+1] = *(const half8*)(p[k] + DIM);
                v[3*k+2] = *(const half8*)(p[k] + 2 * DIM);
            }
            #pragma unroll
            for (int k = 0; k < 3; ++k) {
                #pragma unroll
                for (int j = 0; j < 8; ++j) {
                    a0[j] = fmaf((float)v[3*k+0][j], 1.0f, a0[j]);
                    a1[j] = fmaf((float)v[3*k+1][j], 1.0f, a1[j]);
                    a2[j] = fmaf((float)v[3*k+2][j], 1.0f, a2[j]);
                }
            }
        }
        half8 h0, h1, h2;
        #pragma unroll
        for (int j = 0; j < 8; ++j) {
            h0[j] = (_Float16)a0[j]; h1[j] = (_Float16)a1[j]; h2[j] = (_Float16)a2[j];
        }
        const size_t o = ((size_t)b * SLOTS + slot) * DIM + l16 * 8;
        *(half8*)(msum + o)                 = h0;
        *(half8*)(msum + o + TABSTRIDE)     = h1;
        *(half8*)(msum + o + 2 * TABSTRIDE) = h2;
    }
}

// ---------------------------------------------------------------------------
// Fused hop chain: one 1024-thread block (16 waves) per batch element.
// vc register-cache: each msum table read exactly once (3 passes).
// ---------------------------------------------------------------------------
__global__ __launch_bounds__(1024) void hops_fused(
    const _Float16* __restrict__ msum, float* __restrict__ out)
{
    const int b = blockIdx.x, t = threadIdx.x;
    const int rg = t >> 4, l16 = t & 15, wv = t >> 6, ln = t & 63;
    __shared__ float u_s[DIM];
    __shared__ float probs[SLOTS];
    __shared__ float part[64][DIM + 4];   // 33.8 KB; +4 pad -> 4*rg bank skew
    __shared__ float red[16];

    const _Float16* base = msum + (size_t)b * SLOTS * DIM;
    const int doff = l16 * 8;

    half8 vc[10];                         // 40 VGPR row cache, statically indexed

    // ---- pass A: load tab0 rows, hop0 mean -> u ----
    {
        float acc[8] = {0,0,0,0,0,0,0,0};
        #pragma unroll
        for (int r = 0; r < 10; ++r)
            vc[r] = *(const half8*)(base + (size_t)(rg + 64 * r) * DIM + doff);
        #pragma unroll
        for (int r = 0; r < 10; ++r) {
            #pragma unroll
            for (int j = 0; j < 8; ++j) acc[j] += (float)vc[r][j];
        }
        #pragma unroll
        for (int j = 0; j < 8; ++j) part[rg][doff + j] = acc[j];
        __syncthreads();
        if (t < DIM) {
            float s = 0.f;
            #pragma unroll
            for (int r = 0; r < 64; ++r) s += part[r][t];
            u_s[t] = s * (1.f / SLOTS);
        }
        __syncthreads();
    }

    // ---- hops 1..2 (unrolled so vc[] use is compile-time) ----
    #pragma unroll
    for (int hop = 1; hop < HOPS; ++hop) {
        float u_reg[8];
        #pragma unroll
        for (int j = 0; j < 8; ++j) u_reg[j] = u_s[doff + j];

        // scores from cached rows (tab[hop-1]) -- zero memory traffic
        #pragma unroll
        for (int r = 0; r < 10; ++r) {
            const int m = rg + 64 * r;
            float d = 0.f;
            #pragma unroll
            for (int j = 0; j < 8; ++j) d = fmaf((float)vc[r][j], u_reg[j], d);
            d += __shfl_xor(d, 1); d += __shfl_xor(d, 2);
            d += __shfl_xor(d, 4); d += __shfl_xor(d, 8);
            if (l16 == 0) probs[m] = d;
        }
        __syncthreads();                 // raw scores visible

        // block softmax over SLOTS entries (t<SLOTS owns one)
        float s0 = (t < SLOTS) ? probs[t] : -INFINITY;
        float lmax = s0;
        #pragma unroll
        for (int off = 32; off > 0; off >>= 1) lmax = fmaxf(lmax, __shfl_xor(lmax, off));
        if (ln == 0) red[wv] = lmax;
        __syncthreads();                 // red(max) visible; raw reads all done
        lmax = red[0];
        #pragma unroll
        for (int r = 1; r < 16; ++r) lmax = fmaxf(lmax, red[r]);
        __syncthreads();                 // red free for reuse
        float e0 = (t < SLOTS) ? expf(s0 - lmax) : 0.f;
        if (t < SLOTS) probs[t] = e0;
        float lsum = e0;
        #pragma unroll
        for (int off = 32; off > 0; off >>= 1) lsum += __shfl_xor(lsum, off);
        if (ln == 0) red[wv] = lsum;
        __syncthreads();                 // exp probs + red(sum) visible
        float tot = red[0];
        #pragma unroll
        for (int r = 1; r < 16; ++r) tot += red[r];
        const float inv = 1.0f / tot;

        // weighted sum over tab[hop]; reload vc[] (= next hop's score rows)
        const _Float16* mC = base + (size_t)hop * TABSTRIDE;
        float acc[8] = {0,0,0,0,0,0,0,0};
        #pragma unroll
        for (int r = 0; r < 10; ++r) {
            const int m = rg + 64 * r;
            vc[r] = *(const half8*)(mC + (size_t)m * DIM + doff);
            const float p = probs[m];
            #pragma unroll
            for (int j = 0; j < 8; ++j) acc[j] = fmaf(p, (float)vc[r][j], acc[j]);
        }
        __syncthreads();                 // all probs reads done before next-hop writes
        #pragma unroll
        for (int j = 0; j < 8; ++j) part[rg][doff + j] = acc[j];
        __syncthreads();
        if (t < DIM) {
            float s = 0.f;
            #pragma unroll
            for (int r = 0; r < 64; ++r) s += part[r][t];
            u_s[t] += s * inv;
        }
        __syncthreads();
    }

    if (t < DIM) out[b * DIM + t] = u_s[t];
}

extern "C" void kernel_launch(void* const* d_in, const int* in_sizes, int n_in,
                              void* d_out, int out_size, void* d_ws, size_t ws_size,
                              hipStream_t stream) {
    const float* C     = (const float*)d_in[0];   // [4][VOCAB][DIM] fp32
    const int*   story = (const int*)d_in[1];     // [32][512][6]
    const int*   kb    = (const int*)d_in[2];     // [32][128][64]
    float*       out   = (float*)d_out;           // [32][128] fp32

    _Float16* Ch   = (_Float16*)d_ws;             // [V][3][128] fp16 = 36.8 MiB
    _Float16* msum = Ch + CH_ELEMS;               // [3][NB][SLOTS][128] fp16 = 15 MiB

    convert_k<<<CONV_BLOCKS, 256, 0, stream>>>(C, Ch);
    gather_k<<<GATHER_BLOCKS, 256, 0, stream>>>(Ch, story, kb, msum);
    hops_fused<<<NB, 1024, 0, stream>>>(msum, out);
}

// Round 5
// 213.796 us; speedup vs baseline: 1.3979x; 1.0379x over previous
//
#include <hip/hip_runtime.h>
#include <math.h>

// Problem constants (fixed by setup_inputs)
constexpr int HOPS  = 3;
constexpr int VOCAB = 50257;
constexpr int DIM   = 128;
constexpr int NB    = 32;         // batch
constexpr int NM    = 512;        // story slots
constexpr int NS    = 6;          // tokens per story slot
constexpr int NT    = 128;        // trees
constexpr int NL    = 64;         // tokens per tree
constexpr int SLOTS = NM + NT;    // 640
constexpr size_t TS = (size_t)VOCAB * DIM;              // fp32 table stride in C
constexpr size_t TABSTRIDE = (size_t)NB * SLOTS * DIM;  // msum per-table stride (fp16 elems)

// fp16 compressed tables, token-interleaved: Ch[v][tab][d], tab 0..2 = C[1..3].
constexpr size_t CH_ELEMS = (size_t)VOCAB * 3 * DIM;    // 19,298,688
constexpr int NE8 = (int)(CH_ELEMS / 8);                // 2,412,336 half8 groups

typedef _Float16 half8 __attribute__((ext_vector_type(8)));

constexpr int CONV_BLOCKS  = 2048;            // pure streaming converter
constexpr int TREE_BLOCKS  = NB * NT / 2;     // 2048: 2 trees per block, 2 waves/tree
constexpr int STORY_BLOCKS = NB * NM / 16;    // 1024: 16 slots per block
constexpr int GATHER_BLOCKS = TREE_BLOCKS + STORY_BLOCKS;  // 3072

// ---------------------------------------------------------------------------
// Kernel 1: pure fp32 -> fp16 conversion, C[1..3] -> Ch interleaved [V][3][128].
// Fully coalesced stream: 77 MB read + 39 MB write, HBM-bound (~19 us).
// ---------------------------------------------------------------------------
__global__ __launch_bounds__(256) void convert_k(
    const float* __restrict__ C, _Float16* __restrict__ Ch)
{
    for (int e8 = blockIdx.x * 256 + threadIdx.x; e8 < NE8; e8 += CONV_BLOCKS * 256) {
        const size_t base = (size_t)e8 * 8;
        const size_t v    = base / 384;
        const int    rem  = (int)(base % 384);
        const int    tab  = rem >> 7;             // 0..2
        const int    d    = rem & 127;            // 8-aligned
        const float* src = C + (size_t)(1 + tab) * TS + v * DIM + d;
        float4 f0 = *(const float4*)(src);
        float4 f1 = *(const float4*)(src + 4);
        half8 h;
        h[0]=(_Float16)f0.x; h[1]=(_Float16)f0.y; h[2]=(_Float16)f0.z; h[3]=(_Float16)f0.w;
        h[4]=(_Float16)f1.x; h[5]=(_Float16)f1.y; h[6]=(_Float16)f1.z; h[7]=(_Float16)f1.w;
        *(half8*)(Ch + base) = h;
    }
}

// ---------------------------------------------------------------------------
// Kernel 2: gathers from fp16 Ch. Round-4 lesson: TLP > per-wave ILP here, so
// keep the simple serial round-1 body shape (low VGPR, no chunk arrays) and
// fix the WAVE-LENGTH TAIL instead:
//  - tree blocks (first TREE_BLOCKS): each tree split across TWO waves
//    (32 tokens each -> 8 reads/quarter/table, was 16). Wave partials are
//    combined through 6 KB of LDS. Max quarter read-count 24 (was 48),
//    balanced against story's 18; tree wave count doubles.
//  - story blocks: unchanged round-1 body, 16 slots per block.
// ---------------------------------------------------------------------------
__global__ __launch_bounds__(256) void gather_k(
    const _Float16* __restrict__ Ch, const int* __restrict__ story,
    const int* __restrict__ kb, _Float16* __restrict__ msum)
{
    const int wave = threadIdx.x >> 6, lane = threadIdx.x & 63;
    const int q = lane >> 4, l16 = lane & 15;

    if (blockIdx.x < TREE_BLOCKS) {
        // ---- trees: 2 per block; waves (0,1)->tree0, (2,3)->tree1 ----
        __shared__ float tred[4][3][DIM];             // 6 KB wave partials
        const int tl = wave >> 1, half = wave & 1;
        const int g = blockIdx.x * 2 + tl;            // b*NT + tree, 0..4095
        const int b = g >> 7, tr = g & (NT - 1);

        // this wave's 32 tokens (halves of the 64-token tree), lanes 0..31
        const int tok = (lane < 32) ? kb[(size_t)g * NL + half * 32 + lane] : 0;

        float a0[8] = {0,0,0,0,0,0,0,0};
        float a1[8] = {0,0,0,0,0,0,0,0};
        float a2[8] = {0,0,0,0,0,0,0,0};

        #pragma unroll
        for (int i = 0; i < 8; ++i) {
            const int s = __shfl(tok, q * 8 + i);     // token (q*8+i) of my half
            const _Float16* p = Ch + (size_t)s * (3 * DIM) + l16 * 8;
            half8 v0 = *(const half8*)(p);
            half8 v1 = *(const half8*)(p + DIM);
            half8 v2 = *(const half8*)(p + 2 * DIM);
            #pragma unroll
            for (int j = 0; j < 8; ++j) {
                a0[j] = fmaf((float)v0[j], 1.0f, a0[j]);
                a1[j] = fmaf((float)v1[j], 1.0f, a1[j]);
                a2[j] = fmaf((float)v2[j], 1.0f, a2[j]);
            }
        }
        // cross-quarter reduce (lanes differ only in q bits 4..5)
        #pragma unroll
        for (int j = 0; j < 8; ++j) {
            a0[j] += __shfl_xor(a0[j], 16); a0[j] += __shfl_xor(a0[j], 32);
            a1[j] += __shfl_xor(a1[j], 16); a1[j] += __shfl_xor(a1[j], 32);
            a2[j] += __shfl_xor(a2[j], 16); a2[j] += __shfl_xor(a2[j], 32);
        }
        if (q == 0) {
            #pragma unroll
            for (int j = 0; j < 8; ++j) {
                tred[wave][0][l16 * 8 + j] = a0[j];
                tred[wave][1][l16 * 8 + j] = a1[j];
                tred[wave][2][l16 * 8 + j] = a2[j];
            }
        }
        __syncthreads();
        if (half == 0 && q == 0) {                    // waves 0,2 combine + write
            half8 h0, h1, h2;
            #pragma unroll
            for (int j = 0; j < 8; ++j) {
                const int d = l16 * 8 + j;
                h0[j] = (_Float16)(tred[wave][0][d] + tred[wave + 1][0][d]);
                h1[j] = (_Float16)(tred[wave][1][d] + tred[wave + 1][1][d]);
                h2[j] = (_Float16)(tred[wave][2][d] + tred[wave + 1][2][d]);
            }
            const size_t o = ((size_t)b * SLOTS + NM + tr) * DIM + l16 * 8;
            *(half8*)(msum + o)                 = h0;
            *(half8*)(msum + o + TABSTRIDE)     = h1;
            *(half8*)(msum + o + 2 * TABSTRIDE) = h2;
        }
    } else {
        // ---- story: 16 slots per block, 4 per wave, 1 per quarter ----
        const int sb = blockIdx.x - TREE_BLOCKS;
        const int wbase = sb * 16 + wave * 4;         // first slot of wave
        const int* sidx = story + (size_t)wbase * NS;
        const int tokv = (lane < 4 * NS) ? sidx[lane] : 0;   // 24 coalesced ints

        const int g = wbase + q;                      // b*NM + slot
        const int b = g >> 9, slot = g & (NM - 1);

        float a0[8] = {0,0,0,0,0,0,0,0};
        float a1[8] = {0,0,0,0,0,0,0,0};
        float a2[8] = {0,0,0,0,0,0,0,0};

        #pragma unroll
        for (int i = 0; i < NS; ++i) {
            const int s = __shfl(tokv, q * NS + i);
            const _Float16* p = Ch + (size_t)s * (3 * DIM) + l16 * 8;
            half8 v0 = *(const half8*)(p);
            half8 v1 = *(const half8*)(p + DIM);
            half8 v2 = *(const half8*)(p + 2 * DIM);
            #pragma unroll
            for (int j = 0; j < 8; ++j) {
                a0[j] = fmaf((float)v0[j], 1.0f, a0[j]);
                a1[j] = fmaf((float)v1[j], 1.0f, a1[j]);
                a2[j] = fmaf((float)v2[j], 1.0f, a2[j]);
            }
        }
        half8 h0, h1, h2;
        #pragma unroll
        for (int j = 0; j < 8; ++j) {
            h0[j] = (_Float16)a0[j]; h1[j] = (_Float16)a1[j]; h2[j] = (_Float16)a2[j];
        }
        const size_t o = ((size_t)b * SLOTS + slot) * DIM + l16 * 8;
        *(half8*)(msum + o)                 = h0;
        *(half8*)(msum + o + TABSTRIDE)     = h1;
        *(half8*)(msum + o + 2 * TABSTRIDE) = h2;
    }
}

// ---------------------------------------------------------------------------
// Fused hop chain: one 1024-thread block (16 waves) per batch element.
// vc register-cache: each msum table read exactly once (3 passes).
// ---------------------------------------------------------------------------
__global__ __launch_bounds__(1024) void hops_fused(
    const _Float16* __restrict__ msum, float* __restrict__ out)
{
    const int b = blockIdx.x, t = threadIdx.x;
    const int rg = t >> 4, l16 = t & 15, wv = t >> 6, ln = t & 63;
    __shared__ float u_s[DIM];
    __shared__ float probs[SLOTS];
    __shared__ float part[64][DIM + 4];   // 33.8 KB; +4 pad -> 4*rg bank skew
    __shared__ float red[16];

    const _Float16* base = msum + (size_t)b * SLOTS * DIM;
    const int doff = l16 * 8;

    half8 vc[10];                         // 40 VGPR row cache, statically indexed

    // ---- pass A: load tab0 rows, hop0 mean -> u ----
    {
        float acc[8] = {0,0,0,0,0,0,0,0};
        #pragma unroll
        for (int r = 0; r < 10; ++r)
            vc[r] = *(const half8*)(base + (size_t)(rg + 64 * r) * DIM + doff);
        #pragma unroll
        for (int r = 0; r < 10; ++r) {
            #pragma unroll
            for (int j = 0; j < 8; ++j) acc[j] += (float)vc[r][j];
        }
        #pragma unroll
        for (int j = 0; j < 8; ++j) part[rg][doff + j] = acc[j];
        __syncthreads();
        if (t < DIM) {
            float s = 0.f;
            #pragma unroll
            for (int r = 0; r < 64; ++r) s += part[r][t];
            u_s[t] = s * (1.f / SLOTS);
        }
        __syncthreads();
    }

    // ---- hops 1..2 (unrolled so vc[] use is compile-time) ----
    #pragma unroll
    for (int hop = 1; hop < HOPS; ++hop) {
        float u_reg[8];
        #pragma unroll
        for (int j = 0; j < 8; ++j) u_reg[j] = u_s[doff + j];

        // scores from cached rows (tab[hop-1]) -- zero memory traffic
        #pragma unroll
        for (int r = 0; r < 10; ++r) {
            const int m = rg + 64 * r;
            float d = 0.f;
            #pragma unroll
            for (int j = 0; j < 8; ++j) d = fmaf((float)vc[r][j], u_reg[j], d);
            d += __shfl_xor(d, 1); d += __shfl_xor(d, 2);
            d += __shfl_xor(d, 4); d += __shfl_xor(d, 8);
            if (l16 == 0) probs[m] = d;
        }
        __syncthreads();                 // raw scores visible

        // block softmax over SLOTS entries (t<SLOTS owns one)
        float s0 = (t < SLOTS) ? probs[t] : -INFINITY;
        float lmax = s0;
        #pragma unroll
        for (int off = 32; off > 0; off >>= 1) lmax = fmaxf(lmax, __shfl_xor(lmax, off));
        if (ln == 0) red[wv] = lmax;
        __syncthreads();                 // red(max) visible; raw reads all done
        lmax = red[0];
        #pragma unroll
        for (int r = 1; r < 16; ++r) lmax = fmaxf(lmax, red[r]);
        __syncthreads();                 // red free for reuse
        float e0 = (t < SLOTS) ? expf(s0 - lmax) : 0.f;
        if (t < SLOTS) probs[t] = e0;
        float lsum = e0;
        #pragma unroll
        for (int off = 32; off > 0; off >>= 1) lsum += __shfl_xor(lsum, off);
        if (ln == 0) red[wv] = lsum;
        __syncthreads();                 // exp probs + red(sum) visible
        float tot = red[0];
        #pragma unroll
        for (int r = 1; r < 16; ++r) tot += red[r];
        const float inv = 1.0f / tot;

        // weighted sum over tab[hop]; reload vc[] (= next hop's score rows)
        const _Float16* mC = base + (size_t)hop * TABSTRIDE;
        float acc[8] = {0,0,0,0,0,0,0,0};
        #pragma unroll
        for (int r = 0; r < 10; ++r) {
            const int m = rg + 64 * r;
            vc[r] = *(const half8*)(mC + (size_t)m * DIM + doff);
            const float p = probs[m];
            #pragma unroll
            for (int j = 0; j < 8; ++j) acc[j] = fmaf(p, (float)vc[r][j], acc[j]);
        }
        __syncthreads();                 // all probs reads done before next-hop writes
        #pragma unroll
        for (int j = 0; j < 8; ++j) part[rg][doff + j] = acc[j];
        __syncthreads();
        if (t < DIM) {
            float s = 0.f;
            #pragma unroll
            for (int r = 0; r < 64; ++r) s += part[r][t];
            u_s[t] += s * inv;
        }
        __syncthreads();
    }

    if (t < DIM) out[b * DIM + t] = u_s[t];
}

extern "C" void kernel_launch(void* const* d_in, const int* in_sizes, int n_in,
                              void* d_out, int out_size, void* d_ws, size_t ws_size,
                              hipStream_t stream) {
    const float* C     = (const float*)d_in[0];   // [4][VOCAB][DIM] fp32
    const int*   story = (const int*)d_in[1];     // [32][512][6]
    const int*   kb    = (const int*)d_in[2];     // [32][128][64]
    float*       out   = (float*)d_out;           // [32][128] fp32

    _Float16* Ch   = (_Float16*)d_ws;             // [V][3][128] fp16 = 36.8 MiB
    _Float16* msum = Ch + CH_ELEMS;               // [3][NB][SLOTS][128] fp16 = 15 MiB

    convert_k<<<CONV_BLOCKS, 256, 0, stream>>>(C, Ch);
    gather_k<<<GATHER_BLOCKS, 256, 0, stream>>>(Ch, story, kb, msum);
    hops_fused<<<NB, 1024, 0, stream>>>(msum, out);
}